// Round 2
// baseline (13937.410 us; speedup 1.0000x reference)
//
#include <hip/hip_runtime.h>
#include <hip/hip_fp16.h>
#include <cstdint>

#define B_SZ 4
#define T_SZ 512
#define D_SZ 768
#define H_SZ 768
#define G4   3072           // 4*H
#define V_SZ 50257
#define V_PAD 50304         // 393*128
#define M_SZ 2048           // T*B
#define SCAN_WGS 96

using half8 = __attribute__((ext_vector_type(8))) _Float16;
using f32x4 = __attribute__((ext_vector_type(4))) float;

// ---------------- conversion kernels ----------------

__global__ void conv_A0(const float* __restrict__ reps, _Float16* __restrict__ A0) {
  // A0[(t*4+b)*768 + k] = reps[(b*512 + t)*768 + k]
  int idx = blockIdx.x * blockDim.x + threadIdx.x;
  const int total = M_SZ * D_SZ;
  for (; idx < total; idx += gridDim.x * blockDim.x) {
    int k = idx % D_SZ, m = idx / D_SZ;
    int t = m >> 2, b = m & 3;
    A0[idx] = (_Float16)reps[(b * T_SZ + t) * D_SZ + k];
  }
}

__global__ void conv_cast(const float* __restrict__ src, _Float16* __restrict__ dst, int n) {
  int idx = blockIdx.x * blockDim.x + threadIdx.x;
  for (; idx < n; idx += gridDim.x * blockDim.x) dst[idx] = (_Float16)src[idx];
}

__global__ void conv_head(const float* __restrict__ w, _Float16* __restrict__ dst) {
  int idx = blockIdx.x * blockDim.x + threadIdx.x;
  const int total = V_PAD * H_SZ;
  for (; idx < total; idx += gridDim.x * blockDim.x) {
    int n = idx / H_SZ, k = idx % H_SZ;
    dst[idx] = (n < V_SZ) ? (_Float16)w[n * H_SZ + k] : (_Float16)0.f;
  }
}

// ---------------- f16 MFMA GEMM: C[m][n] = sum_k A[m][k]*B[n][k] + bias[n] ----------------
// A: M x K fp16 row-major, B: N x K fp16 row-major ("B^T input" form).
// mode 0: C row-major M x N fp32.  mode 1: head output C[(b*T + t)*V_SZ + n], m = t*4+b, guard n < Nreal.

__global__ __launch_bounds__(256) void gemm_bt_f16(
    const _Float16* __restrict__ A, const _Float16* __restrict__ B,
    const float* __restrict__ bias, float* __restrict__ C,
    int M, int N, int K, int mode, int Nreal)
{
  __shared__ __align__(16) _Float16 As[128][32];
  __shared__ __align__(16) _Float16 Bs[128][32];
  const int t = threadIdx.x;
  const int lane = t & 63, w = t >> 6;
  const int wr = w >> 1, wc = w & 1;
  const int m0 = blockIdx.x * 128, n0 = blockIdx.y * 128;

  f32x4 acc[4][4] = {};

  const int srow = t >> 2;            // 0..63
  const int scol = (t & 3) * 8;       // half-element offset within 32

  for (int k0 = 0; k0 < K; k0 += 32) {
    uint4 av0 = *(const uint4*)&A[(size_t)(m0 + srow) * K + k0 + scol];
    uint4 av1 = *(const uint4*)&A[(size_t)(m0 + 64 + srow) * K + k0 + scol];
    uint4 bv0 = *(const uint4*)&B[(size_t)(n0 + srow) * K + k0 + scol];
    uint4 bv1 = *(const uint4*)&B[(size_t)(n0 + 64 + srow) * K + k0 + scol];
    __syncthreads();                  // previous iter's frag reads done
    *(uint4*)&As[srow][scol]      = av0;
    *(uint4*)&As[64 + srow][scol] = av1;
    *(uint4*)&Bs[srow][scol]      = bv0;
    *(uint4*)&Bs[64 + srow][scol] = bv1;
    __syncthreads();

    const int fr = lane & 15, k8 = (lane >> 4) * 8;
    half8 af[4], bf[4];
#pragma unroll
    for (int i = 0; i < 4; ++i) {
      af[i] = *(const half8*)&As[wr * 64 + i * 16 + fr][k8];
      bf[i] = *(const half8*)&Bs[wc * 64 + i * 16 + fr][k8];
    }
#pragma unroll
    for (int i = 0; i < 4; ++i)
#pragma unroll
      for (int j = 0; j < 4; ++j)
        acc[i][j] = __builtin_amdgcn_mfma_f32_16x16x32_f16(af[i], bf[j], acc[i][j], 0, 0, 0);
  }

  const int fr = lane & 15, rq = lane >> 4;
#pragma unroll
  for (int i = 0; i < 4; ++i) {
#pragma unroll
    for (int j = 0; j < 4; ++j) {
      int n = n0 + wc * 64 + j * 16 + fr;
      if (n >= Nreal) continue;
      float bv = bias[n];
#pragma unroll
      for (int r = 0; r < 4; ++r) {
        int m = m0 + wr * 64 + i * 16 + rq * 4 + r;
        float v = acc[i][j][r] + bv;
        if (mode == 0) {
          C[(size_t)m * N + n] = v;
        } else {
          int tt = m >> 2, bb = m & 3;
          C[(size_t)(bb * T_SZ + tt) * V_SZ + n] = v;
        }
      }
    }
  }
}

// ---------------- persistent LSTM scan (one layer), plain launch ----------------
// 96 WGs x 256 threads (<< 256 CUs -> co-resident by capacity; no cooperative
// launch needed since the barrier is hand-rolled agent-scope atomics).
// WG owns h-cols [wg*8, wg*8+8). wave wv = gate block (i,f,g,o).
// thread lane covers k = kk*64 + lane, kk = 0..11. W_hh slice held in registers.
// h state: global, double-buffered, layout (k, b) = [768][4] f32, pre-zeroed by memset.

__device__ __forceinline__ void grid_barrier(unsigned* cnt, unsigned* gen) {
  __syncthreads();
  if (threadIdx.x == 0) {
    __threadfence();  // release our global writes (wave 0 holds all hstate/hist writers)
    unsigned g = __hip_atomic_load(gen, __ATOMIC_RELAXED, __HIP_MEMORY_SCOPE_AGENT);
    unsigned arrived = __hip_atomic_fetch_add(cnt, 1u, __ATOMIC_ACQ_REL, __HIP_MEMORY_SCOPE_AGENT);
    if (arrived == SCAN_WGS - 1) {
      __hip_atomic_store(cnt, 0u, __ATOMIC_RELAXED, __HIP_MEMORY_SCOPE_AGENT);
      __hip_atomic_store(gen, g + 1u, __ATOMIC_RELEASE, __HIP_MEMORY_SCOPE_AGENT);
    } else {
      while (__hip_atomic_load(gen, __ATOMIC_ACQUIRE, __HIP_MEMORY_SCOPE_AGENT) == g)
        __builtin_amdgcn_s_sleep(1);
    }
    __threadfence();  // acquire others' writes
  }
  __syncthreads();
}

__global__ __launch_bounds__(256) void lstm_scan(
    const float* __restrict__ xg,     // (2048, 3072): row = t*4+b
    const float* __restrict__ Whh,    // (3072, 768) fp32
    float* __restrict__ hstate,       // 2 * 3072 floats, (k,b) layout, pre-zeroed
    _Float16* __restrict__ hist,      // (2048, 768) fp16, row = t*4+b
    unsigned* __restrict__ bar)       // [cnt, gen], pre-zeroed
{
  __shared__ __align__(16) float hbuf[H_SZ * 4];   // [k][b]
  __shared__ __align__(16) float red[4][8][4][4];  // [gate][c][q][b]
  __shared__ float actv[4][8][4];                  // [gate][c][b]
  __shared__ float cst[8][4];

  const int t = threadIdx.x, lane = t & 63, wv = t >> 6;
  const int j0 = blockIdx.x * 8;

  // preload W_hh slice into registers: w[c][kk] = Whh[wv*768 + j0 + c][kk*64 + lane]
  float wreg[8][12];
#pragma unroll
  for (int c = 0; c < 8; ++c)
#pragma unroll
    for (int kk = 0; kk < 12; ++kk)
      wreg[c][kk] = Whh[(size_t)(wv * H_SZ + j0 + c) * H_SZ + kk * 64 + lane];

  if (t < 32) cst[t >> 2][t & 3] = 0.f;

  const int g_ = t >> 5, c_ = (t >> 2) & 7, b_ = t & 3;

  for (int step = 0; step < T_SZ; ++step) {
    float xgv = 0.f;
    if (t < 128)  // prefetch xg before the barrier (independent of h)
      xgv = xg[(size_t)((step << 2) + b_) * G4 + g_ * H_SZ + j0 + c_];

    grid_barrier(bar, bar + 1);

    const float* hprev = hstate + ((step & 1) ? 3072 : 0);
    {
      const float4* s4 = (const float4*)hprev;
      float4* d4 = (float4*)hbuf;
#pragma unroll
      for (int i = 0; i < 3; ++i) d4[i * 256 + t] = s4[i * 256 + t];
    }
    __syncthreads();

    float4 acc[8];
#pragma unroll
    for (int c = 0; c < 8; ++c) acc[c] = make_float4(0.f, 0.f, 0.f, 0.f);
#pragma unroll
    for (int kk = 0; kk < 12; ++kk) {
      float4 h4 = *(const float4*)&hbuf[(kk * 64 + lane) * 4];
#pragma unroll
      for (int c = 0; c < 8; ++c) {
        float wf = wreg[c][kk];
        acc[c].x = fmaf(wf, h4.x, acc[c].x);
        acc[c].y = fmaf(wf, h4.y, acc[c].y);
        acc[c].z = fmaf(wf, h4.z, acc[c].z);
        acc[c].w = fmaf(wf, h4.w, acc[c].w);
      }
    }
    // butterfly reduce within aligned 16-lane groups
#pragma unroll
    for (int mask = 1; mask <= 8; mask <<= 1) {
#pragma unroll
      for (int c = 0; c < 8; ++c) {
        acc[c].x += __shfl_xor(acc[c].x, mask, 64);
        acc[c].y += __shfl_xor(acc[c].y, mask, 64);
        acc[c].z += __shfl_xor(acc[c].z, mask, 64);
        acc[c].w += __shfl_xor(acc[c].w, mask, 64);
      }
    }
    if ((lane & 15) == 0) {
      int q = lane >> 4;
#pragma unroll
      for (int c = 0; c < 8; ++c) *(float4*)&red[wv][c][q][0] = acc[c];
    }
    __syncthreads();

    if (t < 128) {
      float s = red[g_][c_][0][b_] + red[g_][c_][1][b_] + red[g_][c_][2][b_] + red[g_][c_][3][b_] + xgv;
      float a;
      if (g_ == 2) a = tanhf(s);
      else         a = 1.f / (1.f + expf(-s));
      actv[g_][c_][b_] = a;
    }
    __syncthreads();

    if (t < 32) {
      int c = t >> 2, b = t & 3;
      float iv = actv[0][c][b], fv = actv[1][c][b], gv = actv[2][c][b], ov = actv[3][c][b];
      float cn = fv * cst[c][b] + iv * gv;
      cst[c][b] = cn;
      float hn = ov * tanhf(cn);
      float* hnext = hstate + (((step + 1) & 1) ? 3072 : 0);
      hnext[(j0 + c) * 4 + b] = hn;
      hist[(size_t)((step << 2) + b) * H_SZ + j0 + c] = (_Float16)hn;
    }
    // next iteration's grid_barrier provides the ordering before re-reads
  }
}

// ---------------- launcher ----------------

extern "C" void kernel_launch(void* const* d_in, const int* in_sizes, int n_in,
                              void* d_out, int out_size, void* d_ws, size_t ws_size,
                              hipStream_t stream) {
  const float* reps   = (const float*)d_in[0];
  const float* W_ih   = (const float*)d_in[1];
  const float* W_hh   = (const float*)d_in[2];
  const float* bias   = (const float*)d_in[3];
  const float* head_w = (const float*)d_in[4];
  const float* head_b = (const float*)d_in[5];
  float* out = (float*)d_out;

  char* ws = (char*)d_ws;
  _Float16* A0h    = (_Float16*)(ws + 0);            //  3,145,728 B
  _Float16* Wih_h  = (_Float16*)(ws + 3145728);      //  9,437,184 B (both layers)
  _Float16* Whead  = (_Float16*)(ws + 12582912);     // 77,266,944 B (padded)
  float*    xg     = (float*)   (ws + 89849856);     // 25,165,824 B (reused for both layers)
  _Float16* h0hist = (_Float16*)(ws + 115015680);    //  3,145,728 B
  _Float16* h1hist = (_Float16*)(ws + 118161408);    //  3,145,728 B
  float*    hstate = (float*)   (ws + 121307136);    //     24,576 B
  unsigned* bar    = (unsigned*)(ws + 121331712);    //          8 B

  // conversions
  hipLaunchKernelGGL(conv_A0,   dim3(1024), dim3(256), 0, stream, reps, A0h);
  hipLaunchKernelGGL(conv_cast, dim3(2048), dim3(256), 0, stream, W_ih, Wih_h, 2 * G4 * H_SZ);
  hipLaunchKernelGGL(conv_head, dim3(4096), dim3(256), 0, stream, head_w, Whead);

  // xg0 = A0 * Wih0^T + b0
  hipLaunchKernelGGL(gemm_bt_f16, dim3(16, 24), dim3(256), 0, stream,
                     A0h, Wih_h, bias, xg, M_SZ, G4, H_SZ, 0, G4);

  // layer 0 scan (plain launch; 96 blocks co-resident by capacity)
  hipMemsetAsync(hstate, 0, 24576, stream);
  hipMemsetAsync(bar, 0, 8, stream);
  hipLaunchKernelGGL(lstm_scan, dim3(SCAN_WGS), dim3(256), 0, stream,
                     xg, W_hh, hstate, h0hist, bar);

  // xg1 = h0 * Wih1^T + b1
  hipLaunchKernelGGL(gemm_bt_f16, dim3(16, 24), dim3(256), 0, stream,
                     h0hist, Wih_h + (size_t)G4 * H_SZ, bias + G4, xg, M_SZ, G4, H_SZ, 0, G4);

  // layer 1 scan
  hipMemsetAsync(hstate, 0, 24576, stream);
  hipMemsetAsync(bar, 0, 8, stream);
  hipLaunchKernelGGL(lstm_scan, dim3(SCAN_WGS), dim3(256), 0, stream,
                     xg, W_hh + (size_t)G4 * H_SZ, hstate, h1hist, bar);

  // logits = h1 * head_w^T + head_b  (padded N, permuted store into (B,T,V))
  hipLaunchKernelGGL(gemm_bt_f16, dim3(16, 393), dim3(256), 0, stream,
                     h1hist, Whead, head_b, out, M_SZ, V_PAD, H_SZ, 1, V_SZ);
}